// Round 1
// baseline (485.428 us; speedup 1.0000x reference)
//
#include <hip/hip_runtime.h>
#include <math.h>

#define BB 64
#define NN 8732
#define CC 81

// ---------------- init: zero per-b accumulators ----------------
__global__ void init_kernel(unsigned* acc) {
    int i = threadIdx.x;
    if (i < 4 * BB) acc[i] = 0u;   // num_pos[B], pos_sum[B], loc_cnt[B], loc_sum[B]
}

// ---------------- conf loss: wave per row ----------------
__global__ __launch_bounds__(256) void conf_kernel(
        const float* __restrict__ pred_conf,
        const float* __restrict__ gt_conf,
        float* __restrict__ neg_loss,
        int* __restrict__ num_pos,
        float* __restrict__ pos_sum) {
    const int b    = blockIdx.y;
    const int wave = threadIdx.x >> 6;
    const int lane = threadIdx.x & 63;
    const int rowBase = blockIdx.x * 128 + wave * 32;
    const bool v2 = lane < (CC - 64);     // lanes 0..16 hold a second element

    int   my_cnt = 0;
    float my_sum = 0.f;

    for (int j = 0; j < 32; ++j) {
        int n = rowBase + j;
        if (n >= NN) break;                       // wave-uniform
        size_t base = ((size_t)b * NN + n) * CC;

        float p0 = pred_conf[base + lane];
        float p1 = v2 ? pred_conf[base + 64 + lane] : -INFINITY;
        float gt0 = gt_conf[base];                // broadcast, 1 transaction

        // max reduce
        float m = fmaxf(p0, p1);
        for (int o = 32; o; o >>= 1) m = fmaxf(m, __shfl_down(m, o, 64));
        float M = __shfl(m, 0, 64);

        // sum exp reduce
        float e = expf(p0 - M) + (v2 ? expf(p1 - M) : 0.f);
        for (int o = 32; o; o >>= 1) e += __shfl_down(e, o, 64);

        bool pos = (gt0 == 0.f);                  // non-background
        float dot = 0.f;
        if (pos) {
            float g0 = gt_conf[base + lane];
            float g1 = v2 ? gt_conf[base + 64 + lane] : 0.f;
            float d  = p0 * g0 + (v2 ? p1 * g1 : 0.f);
            for (int o = 32; o; o >>= 1) d += __shfl_down(d, o, 64);
            dot = d;                              // valid in lane 0
        }

        if (lane == 0) {
            float loss = M + logf(e) - (pos ? dot : p0);
            if (pos) { my_cnt++; my_sum += loss; neg_loss[(size_t)b * NN + n] = 0.f; }
            else     {                            neg_loss[(size_t)b * NN + n] = loss; }
        }
    }

    __shared__ int   s_cnt;
    __shared__ float s_sum;
    if (threadIdx.x == 0) { s_cnt = 0; s_sum = 0.f; }
    __syncthreads();
    if (lane == 0 && (my_cnt || my_sum != 0.f)) {
        atomicAdd(&s_cnt, my_cnt);
        atomicAdd(&s_sum, my_sum);
    }
    __syncthreads();
    if (threadIdx.x == 0 && s_cnt) {
        atomicAdd(&num_pos[b], s_cnt);
        atomicAdd(&pos_sum[b], s_sum);
    }
}

// ---------------- loc loss: thread per prior, float4 ----------------
__global__ __launch_bounds__(256) void loc_kernel(
        const float* __restrict__ pred_loc,
        const float* __restrict__ gt_loc,
        float* __restrict__ loc_cnt,
        float* __restrict__ loc_sum) {
    const int b = blockIdx.y;
    const float4* pl = (const float4*)pred_loc;
    const float4* gl = (const float4*)gt_loc;

    float sum = 0.f, cnt = 0.f;
    for (int j = 0; j < 8; ++j) {
        int n = blockIdx.x * 2048 + j * 256 + threadIdx.x;
        if (n < NN) {
            size_t idx = (size_t)b * NN + n;
            float4 p = pl[idx];
            float4 g = gl[idx];
            bool any = false;
            float pv[4] = {p.x, p.y, p.z, p.w};
            float gv[4] = {g.x, g.y, g.z, g.w};
            #pragma unroll
            for (int c = 0; c < 4; ++c) {
                if (gv[c] != 0.f) {
                    any = true;
                    float d = fabsf(pv[c] - gv[c]);
                    sum += (d < 1.f) ? 0.5f * d * d : d - 0.5f;
                }
            }
            if (any) cnt += 1.f;
        }
    }
    // wave reduce then block reduce
    for (int o = 32; o; o >>= 1) {
        sum += __shfl_down(sum, o, 64);
        cnt += __shfl_down(cnt, o, 64);
    }
    __shared__ float s_sum, s_cnt;
    if (threadIdx.x == 0) { s_sum = 0.f; s_cnt = 0.f; }
    __syncthreads();
    if ((threadIdx.x & 63) == 0) {
        atomicAdd(&s_sum, sum);
        atomicAdd(&s_cnt, cnt);
    }
    __syncthreads();
    if (threadIdx.x == 0) {
        atomicAdd(&loc_sum[b], s_sum);
        atomicAdd(&loc_cnt[b], s_cnt);
    }
}

// ---------------- per-batch radix select + finalize ----------------
__global__ __launch_bounds__(256) void select_kernel(
        const float* __restrict__ neg_loss,
        const int*   __restrict__ num_pos,
        const float* __restrict__ pos_sum,
        const float* __restrict__ loc_cnt,
        const float* __restrict__ loc_sum,
        float* __restrict__ per_b) {
    const int b = blockIdx.x;
    __shared__ unsigned vals[NN];        // 34928 B
    __shared__ unsigned hist[256];
    __shared__ unsigned sh_prefix, sh_r;
    __shared__ float    s_part[4];

    for (int i = threadIdx.x; i < NN; i += 256)
        vals[i] = __float_as_uint(neg_loss[(size_t)b * NN + i]);

    int np = num_pos[b];
    int k  = min(3 * np, NN - 1);        // clip(int(num_neg), 0, N-1)
    if (threadIdx.x == 0) { sh_prefix = 0u; sh_r = (unsigned)k; }
    __syncthreads();

    unsigned prefix_mask = 0u;
    for (int p = 3; p >= 0; --p) {
        hist[threadIdx.x] = 0u;
        __syncthreads();
        unsigned pref = sh_prefix;
        for (int i = threadIdx.x; i < NN; i += 256) {
            unsigned v = vals[i];
            if ((v & prefix_mask) == pref)
                atomicAdd(&hist[(v >> (8 * p)) & 255u], 1u);
        }
        __syncthreads();
        if (threadIdx.x == 0) {
            unsigned r = sh_r;
            int bin = 255;
            for (; bin > 0; --bin) {
                unsigned c = hist[bin];
                if (r < c) break;
                r -= c;
            }
            sh_r = r;
            sh_prefix = pref | ((unsigned)bin << (8 * p));
        }
        __syncthreads();
        prefix_mask |= 0xFFu << (8 * p);
    }

    float thresh = __uint_as_float(sh_prefix);   // exact (k+1)-th largest
    float s = 0.f;
    for (int i = threadIdx.x; i < NN; i += 256) {
        float v = __uint_as_float(vals[i]);
        if (v > thresh) s += v;                  // strict >, matches reference
    }
    for (int o = 32; o; o >>= 1) s += __shfl_down(s, o, 64);
    if ((threadIdx.x & 63) == 0) s_part[threadIdx.x >> 6] = s;
    __syncthreads();
    if (threadIdx.x == 0) {
        float neg_sum = s_part[0] + s_part[1] + s_part[2] + s_part[3];
        float npf = (float)np;
        float nnf = 3.0f * npf;
        per_b[b] = pos_sum[b] / npf + neg_sum / nnf + loc_sum[b] / loc_cnt[b];
    }
}

// ---------------- final mean over batch ----------------
__global__ void finalize_kernel(const float* __restrict__ per_b, float* __restrict__ out) {
    float v = (threadIdx.x < BB) ? per_b[threadIdx.x] : 0.f;
    for (int o = 32; o; o >>= 1) v += __shfl_down(v, o, 64);
    if (threadIdx.x == 0) out[0] = v * (1.0f / BB);
}

extern "C" void kernel_launch(void* const* d_in, const int* in_sizes, int n_in,
                              void* d_out, int out_size, void* d_ws, size_t ws_size,
                              hipStream_t stream) {
    const float* pred_conf = (const float*)d_in[0];
    const float* pred_loc  = (const float*)d_in[1];
    const float* gt_conf   = (const float*)d_in[2];
    const float* gt_loc    = (const float*)d_in[3];

    // workspace layout
    float* neg      = (float*)d_ws;                 // B*N floats
    int*   num_pos  = (int*)(neg + (size_t)BB * NN);
    float* pos_sum  = (float*)(num_pos + BB);
    float* loc_cnt  = pos_sum + BB;
    float* loc_sum  = loc_cnt + BB;
    float* per_b    = loc_sum + BB;

    init_kernel<<<1, 256, 0, stream>>>((unsigned*)num_pos);

    dim3 cgrid((NN + 127) / 128, BB);               // 69 x 64
    conf_kernel<<<cgrid, 256, 0, stream>>>(pred_conf, gt_conf, neg, num_pos, pos_sum);

    dim3 lgrid((NN + 2047) / 2048, BB);             // 5 x 64
    loc_kernel<<<lgrid, 256, 0, stream>>>(pred_loc, gt_loc, loc_cnt, loc_sum);

    select_kernel<<<BB, 256, 0, stream>>>(neg, num_pos, pos_sum, loc_cnt, loc_sum, per_b);

    finalize_kernel<<<1, 64, 0, stream>>>(per_b, (float*)d_out);
}

// Round 2
// 434.153 us; speedup vs baseline: 1.1181x; 1.1181x over previous
//
#include <hip/hip_runtime.h>
#include <math.h>

#define BB 64
#define NN 8732
#define CC 81
#define ROWS_PER_BLOCK 128

// ---------------- init: zero per-b accumulators ----------------
__global__ void init_kernel(unsigned* acc) {
    int i = threadIdx.x;
    if (i < 4 * BB) acc[i] = 0u;   // num_pos[B], pos_sum[B], loc_cnt[B], loc_sum[B]
}

// ---------------- conf loss: 2 threads per row, LDS-staged ----------------
__global__ __launch_bounds__(256) void conf_kernel(
        const float* __restrict__ pred_conf,
        const float* __restrict__ gt_conf,
        float* __restrict__ neg_loss,
        int* __restrict__ num_pos,
        float* __restrict__ pos_sum) {
    __shared__ float lbuf[ROWS_PER_BLOCK * CC + 8];
    __shared__ int   s_cnt;
    __shared__ float s_sum;

    const int b       = blockIdx.y;
    const int rowBase = blockIdx.x * ROWS_PER_BLOCK;
    const int nrows   = min(ROWS_PER_BLOCK, NN - rowBase);
    const size_t TOTF = (size_t)BB * NN * CC;

    if (threadIdx.x == 0) { s_cnt = 0; s_sum = 0.f; }

    // ---- stage nrows*81 floats into LDS with float4 loads (aligned superset) ----
    const size_t seg = ((size_t)b * NN + rowBase) * CC;   // first float we need
    const int    cnt = nrows * CC;
    const size_t a0  = seg & ~(size_t)3;                  // 16B-aligned start
    const int  shift = (int)(seg - a0);                   // 0..3
    const int   tot4 = (shift + cnt + 3) >> 2;

    const float4* g4 = (const float4*)(pred_conf + a0);
    float4*       l4 = (float4*)lbuf;
    for (int i = threadIdx.x; i < tot4; i += 256) {
        size_t gf = a0 + 4 * (size_t)i;
        if (gf + 4 <= TOTF) {
            l4[i] = g4[i];
        } else {
            #pragma unroll
            for (int c = 0; c < 4; ++c)
                lbuf[4 * i + c] = (gf + c < TOTF) ? pred_conf[gf + c] : 0.f;
        }
    }
    __syncthreads();

    // ---- compute: thread pair (2r, 2r+1) handles row r ----
    const int r = threadIdx.x >> 1;
    const int h = threadIdx.x & 1;
    if (r < nrows) {
        const float* row = lbuf + shift + r * CC;
        const int c0 = h ? 41 : 0;
        const int c1 = h ? CC : 41;

        // prefetch gt0 early (scattered, both lanes same address -> 1 txn)
        const size_t gbase = ((size_t)b * NN + rowBase + r) * CC;
        const float gt0 = gt_conf[gbase];

        float m = -1e30f;
        for (int c = c0; c < c1; ++c) m = fmaxf(m, row[c]);
        m = fmaxf(m, __shfl_xor(m, 1, 64));

        float e = 0.f;
        for (int c = c0; c < c1; ++c) e += __expf(row[c] - m);
        e += __shfl_xor(e, 1, 64);

        const bool pos = (gt0 == 0.f);   // background prob 0 => positive prior
        float x_sel;
        if (pos) {
            float d = 0.f;
            for (int c = c0; c < c1; ++c) d += gt_conf[gbase + c] * row[c];
            d += __shfl_xor(d, 1, 64);
            x_sel = d;                   // pred at label (gt one-hot)
        } else {
            x_sel = row[0];              // background: label 0
        }

        const float loss = m + __logf(e) - x_sel;
        if (h == 0) {
            neg_loss[(size_t)b * NN + rowBase + r] = pos ? 0.f : loss;
            if (pos) {
                atomicAdd(&s_cnt, 1);
                atomicAdd(&s_sum, loss);
            }
        }
    }
    __syncthreads();
    if (threadIdx.x == 0 && s_cnt) {
        atomicAdd(&num_pos[b], s_cnt);
        atomicAdd(&pos_sum[b], s_sum);
    }
}

// ---------------- loc loss: thread per prior, float4 ----------------
__global__ __launch_bounds__(256) void loc_kernel(
        const float* __restrict__ pred_loc,
        const float* __restrict__ gt_loc,
        float* __restrict__ loc_cnt,
        float* __restrict__ loc_sum) {
    const int b = blockIdx.y;
    const float4* pl = (const float4*)pred_loc;
    const float4* gl = (const float4*)gt_loc;

    float sum = 0.f, cnt = 0.f;
    for (int j = 0; j < 8; ++j) {
        int n = blockIdx.x * 2048 + j * 256 + threadIdx.x;
        if (n < NN) {
            size_t idx = (size_t)b * NN + n;
            float4 p = pl[idx];
            float4 g = gl[idx];
            bool any = false;
            float pv[4] = {p.x, p.y, p.z, p.w};
            float gv[4] = {g.x, g.y, g.z, g.w};
            #pragma unroll
            for (int c = 0; c < 4; ++c) {
                if (gv[c] != 0.f) {
                    any = true;
                    float d = fabsf(pv[c] - gv[c]);
                    sum += (d < 1.f) ? 0.5f * d * d : d - 0.5f;
                }
            }
            if (any) cnt += 1.f;
        }
    }
    for (int o = 32; o; o >>= 1) {
        sum += __shfl_down(sum, o, 64);
        cnt += __shfl_down(cnt, o, 64);
    }
    __shared__ float s_sum, s_cnt;
    if (threadIdx.x == 0) { s_sum = 0.f; s_cnt = 0.f; }
    __syncthreads();
    if ((threadIdx.x & 63) == 0) {
        atomicAdd(&s_sum, sum);
        atomicAdd(&s_cnt, cnt);
    }
    __syncthreads();
    if (threadIdx.x == 0) {
        atomicAdd(&loc_sum[b], s_sum);
        atomicAdd(&loc_cnt[b], s_cnt);
    }
}

// ---------------- per-batch radix select + finalize ----------------
__global__ __launch_bounds__(256) void select_kernel(
        const float* __restrict__ neg_loss,
        const int*   __restrict__ num_pos,
        const float* __restrict__ pos_sum,
        const float* __restrict__ loc_cnt,
        const float* __restrict__ loc_sum,
        float* __restrict__ per_b) {
    const int b   = blockIdx.x;
    const int tid = threadIdx.x;
    const int lane = tid & 63;
    __shared__ unsigned vals[NN];        // 34928 B
    __shared__ unsigned hist[256];
    __shared__ unsigned scan[256];
    __shared__ unsigned sh_prefix, sh_r;
    __shared__ float    s_part[4];

    for (int i = tid; i < NN; i += 256)
        vals[i] = __float_as_uint(neg_loss[(size_t)b * NN + i]);

    const int np = num_pos[b];
    const int k  = min(3 * np, NN - 1);  // clip(int(num_neg), 0, N-1)
    if (tid == 0) { sh_prefix = 0u; sh_r = (unsigned)k; }
    __syncthreads();

    unsigned prefix_mask = 0u;
    for (int p = 3; p >= 0; --p) {
        const unsigned pref = sh_prefix;
        const unsigned r    = sh_r;
        hist[tid] = 0u;
        __syncthreads();

        // ballot-aggregated histogram: one atomic per distinct bin per wave
        for (int i0 = 0; i0 < NN; i0 += 256) {
            const int i = i0 + tid;
            const bool act = (i < NN) && ((vals[i] & prefix_mask) == pref);
            const unsigned v   = act ? vals[i] : 0u;
            const unsigned bin = (v >> (8 * p)) & 255u;
            unsigned long long mm = __ballot(act);
            #pragma unroll
            for (int bit = 0; bit < 8; ++bit) {
                unsigned long long s = __ballot(act && ((bin >> bit) & 1u));
                mm &= ((bin >> bit) & 1u) ? s : ~s;
            }
            if (act && ((mm & ((1ull << lane) - 1ull)) == 0ull))
                atomicAdd(&hist[bin], (unsigned)__popcll(mm));
        }
        __syncthreads();

        // parallel inclusive suffix sum: scan[i] = sum_{j>=i} hist[j]
        scan[tid] = hist[tid];
        __syncthreads();
        for (int off = 1; off < 256; off <<= 1) {
            unsigned add = (tid + off < 256) ? scan[tid + off] : 0u;
            __syncthreads();
            scan[tid] += add;
            __syncthreads();
        }
        // pick bin with Sinc[bin+1] <= r < Sinc[bin]
        const unsigned Si  = scan[tid];
        const unsigned Si1 = (tid < 255) ? scan[tid + 1] : 0u;
        __syncthreads();
        if (Si1 <= r && r < Si) {
            sh_r = r - Si1;
            sh_prefix = pref | ((unsigned)tid << (8 * p));
        }
        __syncthreads();
        prefix_mask |= 0xFFu << (8 * p);
    }

    const float thresh = __uint_as_float(sh_prefix);   // exact (k+1)-th largest
    float s = 0.f;
    for (int i = tid; i < NN; i += 256) {
        float v = __uint_as_float(vals[i]);
        if (v > thresh) s += v;                        // strict >, matches reference
    }
    for (int o = 32; o; o >>= 1) s += __shfl_down(s, o, 64);
    if (lane == 0) s_part[tid >> 6] = s;
    __syncthreads();
    if (tid == 0) {
        float neg_sum = s_part[0] + s_part[1] + s_part[2] + s_part[3];
        float npf = (float)np;
        per_b[b] = pos_sum[b] / npf + neg_sum / (3.0f * npf) + loc_sum[b] / loc_cnt[b];
    }
}

// ---------------- final mean over batch ----------------
__global__ void finalize_kernel(const float* __restrict__ per_b, float* __restrict__ out) {
    float v = (threadIdx.x < BB) ? per_b[threadIdx.x] : 0.f;
    for (int o = 32; o; o >>= 1) v += __shfl_down(v, o, 64);
    if (threadIdx.x == 0) out[0] = v * (1.0f / BB);
}

extern "C" void kernel_launch(void* const* d_in, const int* in_sizes, int n_in,
                              void* d_out, int out_size, void* d_ws, size_t ws_size,
                              hipStream_t stream) {
    const float* pred_conf = (const float*)d_in[0];
    const float* pred_loc  = (const float*)d_in[1];
    const float* gt_conf   = (const float*)d_in[2];
    const float* gt_loc    = (const float*)d_in[3];

    float* neg      = (float*)d_ws;                 // B*N floats
    int*   num_pos  = (int*)(neg + (size_t)BB * NN);
    float* pos_sum  = (float*)(num_pos + BB);
    float* loc_cnt  = pos_sum + BB;
    float* loc_sum  = loc_cnt + BB;
    float* per_b    = loc_sum + BB;

    init_kernel<<<1, 256, 0, stream>>>((unsigned*)num_pos);

    dim3 cgrid((NN + ROWS_PER_BLOCK - 1) / ROWS_PER_BLOCK, BB);   // 69 x 64
    conf_kernel<<<cgrid, 256, 0, stream>>>(pred_conf, gt_conf, neg, num_pos, pos_sum);

    dim3 lgrid((NN + 2047) / 2048, BB);             // 5 x 64
    loc_kernel<<<lgrid, 256, 0, stream>>>(pred_loc, gt_loc, loc_cnt, loc_sum);

    select_kernel<<<BB, 256, 0, stream>>>(neg, num_pos, pos_sum, loc_cnt, loc_sum, per_b);

    finalize_kernel<<<1, 64, 0, stream>>>(per_b, (float*)d_out);
}

// Round 3
// 425.114 us; speedup vs baseline: 1.1419x; 1.0213x over previous
//
#include <hip/hip_runtime.h>
#include <math.h>

#define BB 64
#define NN 8732
#define CC 81
#define ROWS 64                    // rows per conf block
#define CBX ((NN + ROWS - 1) / ROWS)   // 137 conf blocks per batch
#define LBX 5                          // loc blocks per batch (2048 priors each)

// ---------------- init: zero per-b accumulators + output ----------------
__global__ void init_kernel(unsigned* acc, float* out) {
    int i = threadIdx.x;
    if (i < 4 * BB) acc[i] = 0u;   // num_pos[B], pos_sum[B], loc_cnt[B], loc_sum[B]
    if (i == 0) out[0] = 0.f;
}

// ---------------- fused conf + loc ----------------
__global__ __launch_bounds__(256) void fused_kernel(
        const float* __restrict__ pred_conf,
        const float* __restrict__ gt_conf,
        const float* __restrict__ pred_loc,
        const float* __restrict__ gt_loc,
        float* __restrict__ neg_loss,
        int* __restrict__ num_pos,
        float* __restrict__ pos_sum,
        float* __restrict__ loc_cnt,
        float* __restrict__ loc_sum) {
    const int b   = blockIdx.y;
    const int tid = threadIdx.x;

    if (blockIdx.x >= CBX) {
        // ================= loc part =================
        const int lb = blockIdx.x - CBX;
        const float4* pl = (const float4*)pred_loc;
        const float4* gl = (const float4*)gt_loc;
        float sum = 0.f, cnt = 0.f;
        #pragma unroll
        for (int j = 0; j < 8; ++j) {
            int n = lb * 2048 + j * 256 + tid;
            if (n < NN) {
                size_t idx = (size_t)b * NN + n;
                float4 p = pl[idx];
                float4 g = gl[idx];
                bool any = false;
                float pv[4] = {p.x, p.y, p.z, p.w};
                float gv[4] = {g.x, g.y, g.z, g.w};
                #pragma unroll
                for (int c = 0; c < 4; ++c) {
                    if (gv[c] != 0.f) {
                        any = true;
                        float d = fabsf(pv[c] - gv[c]);
                        sum += (d < 1.f) ? 0.5f * d * d : d - 0.5f;
                    }
                }
                if (any) cnt += 1.f;
            }
        }
        for (int o = 32; o; o >>= 1) {
            sum += __shfl_down(sum, o, 64);
            cnt += __shfl_down(cnt, o, 64);
        }
        __shared__ float ls_sum, ls_cnt;
        if (tid == 0) { ls_sum = 0.f; ls_cnt = 0.f; }
        __syncthreads();
        if ((tid & 63) == 0) { atomicAdd(&ls_sum, sum); atomicAdd(&ls_cnt, cnt); }
        __syncthreads();
        if (tid == 0) { atomicAdd(&loc_sum[b], ls_sum); atomicAdd(&loc_cnt[b], ls_cnt); }
        return;
    }

    // ================= conf part =================
    __shared__ float lbuf[ROWS * CC + 8];
    __shared__ int   s_cnt;
    __shared__ float s_sum;

    const int rowBase = blockIdx.x * ROWS;
    const int nrows   = min(ROWS, NN - rowBase);
    const size_t TOTF = (size_t)BB * NN * CC;

    if (tid == 0) { s_cnt = 0; s_sum = 0.f; }

    // stage nrows*81 floats into LDS with float4 loads (aligned superset)
    const size_t seg = ((size_t)b * NN + rowBase) * CC;
    const int    cnt = nrows * CC;
    const size_t a0  = seg & ~(size_t)3;
    const int  shift = (int)(seg - a0);
    const int   tot4 = (shift + cnt + 3) >> 2;

    const float4* g4 = (const float4*)(pred_conf + a0);
    float4*       l4 = (float4*)lbuf;
    for (int i = tid; i < tot4; i += 256) {
        size_t gf = a0 + 4 * (size_t)i;
        if (gf + 4 <= TOTF) {
            l4[i] = g4[i];
        } else {
            #pragma unroll
            for (int c = 0; c < 4; ++c)
                lbuf[4 * i + c] = (gf + c < TOTF) ? pred_conf[gf + c] : 0.f;
        }
    }
    __syncthreads();

    // 4 threads per row; thread h covers [c0, c0+nc): h=0 -> 21 elems, else 20
    const int r = tid >> 2;
    const int h = tid & 3;
    if (r < nrows) {
        const int c0 = h * 20 + (h > 0 ? 1 : 0);
        const int nc = (h == 0) ? 21 : 20;
        const float* row = lbuf + shift + r * CC;
        const size_t gbase = ((size_t)b * NN + rowBase + r) * CC;
        const float gt0 = gt_conf[gbase];      // quad reads same addr -> broadcast

        float v[21];
        #pragma unroll
        for (int j = 0; j < 21; ++j)
            v[j] = (j < nc) ? row[c0 + j] : -1e30f;

        float m = v[0];
        #pragma unroll
        for (int j = 1; j < 21; ++j) m = fmaxf(m, v[j]);
        m = fmaxf(m, __shfl_xor(m, 1, 64));
        m = fmaxf(m, __shfl_xor(m, 2, 64));

        float e = 0.f;
        #pragma unroll
        for (int j = 0; j < 21; ++j) e += __expf(v[j] - m);   // padded -> exp->0
        e += __shfl_xor(e, 1, 64);
        e += __shfl_xor(e, 2, 64);

        const bool pos = (gt0 == 0.f);         // background prob 0 => positive prior
        float x_sel = v[0];                    // row[0] valid on h==0 (the writer lane)
        if (pos) {
            float d = 0.f;
            #pragma unroll
            for (int j = 0; j < 21; ++j)
                if (j < nc) d += gt_conf[gbase + c0 + j] * v[j];
            d += __shfl_xor(d, 1, 64);
            d += __shfl_xor(d, 2, 64);
            x_sel = d;                         // pred at one-hot label
        }

        const float loss = m + __logf(e) - x_sel;
        if (h == 0) {
            neg_loss[(size_t)b * NN + rowBase + r] = pos ? 0.f : loss;
            if (pos) { atomicAdd(&s_cnt, 1); atomicAdd(&s_sum, loss); }
        }
    }
    __syncthreads();
    if (tid == 0 && s_cnt) {
        atomicAdd(&num_pos[b], s_cnt);
        atomicAdd(&pos_sum[b], s_sum);
    }
}

// ---------------- per-batch radix select + finalize (atomic mean) ----------------
__global__ __launch_bounds__(256) void select_kernel(
        const float* __restrict__ neg_loss,
        const int*   __restrict__ num_pos,
        const float* __restrict__ pos_sum,
        const float* __restrict__ loc_cnt,
        const float* __restrict__ loc_sum,
        float* __restrict__ out) {
    const int b    = blockIdx.x;
    const int tid  = threadIdx.x;
    const int lane = tid & 63;
    __shared__ unsigned vals[NN];        // 34928 B
    __shared__ unsigned hist[256];
    __shared__ unsigned sh_prefix, sh_r;
    __shared__ float    s_part[4];

    #pragma unroll 4
    for (int i = tid; i < NN; i += 256)
        vals[i] = __float_as_uint(neg_loss[(size_t)b * NN + i]);

    const int np = num_pos[b];
    const int k  = min(3 * np, NN - 1);  // clip(int(num_neg), 0, N-1)
    if (tid == 0) { sh_prefix = 0u; sh_r = (unsigned)k; }
    __syncthreads();

    unsigned prefix_mask = 0u;
    for (int p = 3; p >= 0; --p) {
        const unsigned pref = sh_prefix;
        const unsigned r    = sh_r;
        hist[tid] = 0u;
        __syncthreads();

        // ballot-aggregated histogram: one atomic per distinct bin per wave
        for (int i0 = 0; i0 < NN; i0 += 256) {
            const int i = i0 + tid;
            const bool act = (i < NN) && ((vals[i] & prefix_mask) == pref);
            const unsigned v   = act ? vals[i] : 0u;
            const unsigned bin = (v >> (8 * p)) & 255u;
            unsigned long long mm = __ballot(act);
            #pragma unroll
            for (int bit = 0; bit < 8; ++bit) {
                unsigned long long s = __ballot(act && ((bin >> bit) & 1u));
                mm &= ((bin >> bit) & 1u) ? s : ~s;
            }
            if (act && ((mm & ((1ull << lane) - 1ull)) == 0ull))
                atomicAdd(&hist[bin], (unsigned)__popcll(mm));
        }
        __syncthreads();

        // wave-0 suffix scan over 256 bins (4 bins/lane) + bin pick
        if (tid < 64) {
            const unsigned h0 = hist[4 * tid + 0];
            const unsigned h1 = hist[4 * tid + 1];
            const unsigned h2 = hist[4 * tid + 2];
            const unsigned h3 = hist[4 * tid + 3];
            unsigned T = h0 + h1 + h2 + h3;
            #pragma unroll
            for (int off = 1; off < 64; off <<= 1) {
                unsigned t2 = __shfl_down(T, off, 64);
                if (tid + off < 64) T += t2;
            }
            unsigned Tn = __shfl_down(T, 1, 64);
            if (tid == 63) Tn = 0u;
            const unsigned S4 = Tn, S3 = S4 + h3, S2 = S3 + h2, S1 = S2 + h1, S0 = S1 + h0;
            int bin = -1; unsigned Slo = 0u;
            if      (S1 <= r && r < S0) { bin = 4 * tid + 0; Slo = S1; }
            else if (S2 <= r && r < S1) { bin = 4 * tid + 1; Slo = S2; }
            else if (S3 <= r && r < S2) { bin = 4 * tid + 2; Slo = S3; }
            else if (S4 <= r && r < S3) { bin = 4 * tid + 3; Slo = S4; }
            if (bin >= 0) {
                sh_r = r - Slo;
                sh_prefix = pref | ((unsigned)bin << (8 * p));
            }
        }
        __syncthreads();
        prefix_mask |= 0xFFu << (8 * p);
    }

    const float thresh = __uint_as_float(sh_prefix);   // exact (k+1)-th largest
    float s = 0.f;
    #pragma unroll 4
    for (int i = tid; i < NN; i += 256) {
        float v = __uint_as_float(vals[i]);
        if (v > thresh) s += v;                        // strict >, matches reference
    }
    for (int o = 32; o; o >>= 1) s += __shfl_down(s, o, 64);
    if (lane == 0) s_part[tid >> 6] = s;
    __syncthreads();
    if (tid == 0) {
        float neg_sum = s_part[0] + s_part[1] + s_part[2] + s_part[3];
        float npf = (float)np;
        float res = pos_sum[b] / npf + neg_sum / (3.0f * npf) + loc_sum[b] / loc_cnt[b];
        atomicAdd(out, res * (1.0f / BB));
    }
}

extern "C" void kernel_launch(void* const* d_in, const int* in_sizes, int n_in,
                              void* d_out, int out_size, void* d_ws, size_t ws_size,
                              hipStream_t stream) {
    const float* pred_conf = (const float*)d_in[0];
    const float* pred_loc  = (const float*)d_in[1];
    const float* gt_conf   = (const float*)d_in[2];
    const float* gt_loc    = (const float*)d_in[3];

    float* neg      = (float*)d_ws;                 // B*N floats
    int*   num_pos  = (int*)(neg + (size_t)BB * NN);
    float* pos_sum  = (float*)(num_pos + BB);
    float* loc_cnt  = pos_sum + BB;
    float* loc_sum  = loc_cnt + BB;

    init_kernel<<<1, 256, 0, stream>>>((unsigned*)num_pos, (float*)d_out);

    dim3 fgrid(CBX + LBX, BB);                      // 142 x 64
    fused_kernel<<<fgrid, 256, 0, stream>>>(pred_conf, gt_conf, pred_loc, gt_loc,
                                            neg, num_pos, pos_sum, loc_cnt, loc_sum);

    select_kernel<<<BB, 256, 0, stream>>>(neg, num_pos, pos_sum, loc_cnt, loc_sum,
                                          (float*)d_out);
}

// Round 4
// 415.904 us; speedup vs baseline: 1.1672x; 1.0221x over previous
//
#include <hip/hip_runtime.h>
#include <math.h>

#define BB 64
#define NN 8732
#define CC 81
#define TR 64                       // rows per tile
#define TPB 4                       // tiles per block (software pipeline depth)
#define CBX ((NN + TR * TPB - 1) / (TR * TPB))   // 35 conf blocks per batch
#define LBX 5                       // loc blocks per batch (2048 priors each)

// ---------------- init: zero per-b accumulators + output ----------------
__global__ void init_kernel(unsigned* acc, float* out) {
    int i = threadIdx.x;
    if (i < 4 * BB) acc[i] = 0u;   // num_pos[B], pos_sum[B], loc_cnt[B], loc_sum[B]
    if (i == 0) out[0] = 0.f;
}

__device__ __forceinline__ float4 ld4g(const float* __restrict__ p, size_t gf, size_t TOTF) {
    if (gf + 4 <= TOTF) return *(const float4*)(p + gf);
    float4 r; float* rp = (float*)&r;
    #pragma unroll
    for (int c = 0; c < 4; ++c) rp[c] = (gf + c < TOTF) ? p[gf + c] : 0.f;
    return r;
}

// ---------------- fused conf + loc ----------------
__global__ __launch_bounds__(256) void fused_kernel(
        const float* __restrict__ pred_conf,
        const float* __restrict__ gt_conf,
        const float* __restrict__ pred_loc,
        const float* __restrict__ gt_loc,
        float* __restrict__ neg_loss,
        int* __restrict__ num_pos,
        float* __restrict__ pos_sum,
        float* __restrict__ loc_cnt,
        float* __restrict__ loc_sum) {
    const int b   = blockIdx.y;
    const int tid = threadIdx.x;

    if (blockIdx.x >= CBX) {
        // ================= loc part =================
        const int lb = blockIdx.x - CBX;
        const float4* pl = (const float4*)pred_loc;
        const float4* gl = (const float4*)gt_loc;
        float sum = 0.f, cnt = 0.f;
        #pragma unroll
        for (int j = 0; j < 8; ++j) {
            int n = lb * 2048 + j * 256 + tid;
            if (n < NN) {
                size_t idx = (size_t)b * NN + n;
                float4 p = pl[idx];
                float4 g = gl[idx];
                bool any = false;
                float pv[4] = {p.x, p.y, p.z, p.w};
                float gv[4] = {g.x, g.y, g.z, g.w};
                #pragma unroll
                for (int c = 0; c < 4; ++c) {
                    if (gv[c] != 0.f) {
                        any = true;
                        float d = fabsf(pv[c] - gv[c]);
                        sum += (d < 1.f) ? 0.5f * d * d : d - 0.5f;
                    }
                }
                if (any) cnt += 1.f;
            }
        }
        for (int o = 32; o; o >>= 1) {
            sum += __shfl_down(sum, o, 64);
            cnt += __shfl_down(cnt, o, 64);
        }
        __shared__ float ls_sum, ls_cnt;
        if (tid == 0) { ls_sum = 0.f; ls_cnt = 0.f; }
        __syncthreads();
        if ((tid & 63) == 0) { atomicAdd(&ls_sum, sum); atomicAdd(&ls_cnt, cnt); }
        __syncthreads();
        if (tid == 0) { atomicAdd(&loc_sum[b], ls_sum); atomicAdd(&loc_cnt[b], ls_cnt); }
        return;
    }

    // ================= conf part: 4-tile software pipeline =================
    __shared__ float lbuf[TR * CC + 8];
    __shared__ int   s_cnt;
    __shared__ float s_sum;
    float4* l4 = (float4*)lbuf;

    const size_t TOTF = (size_t)BB * NN * CC;
    const int tile0 = blockIdx.x * TPB;
    const int r = tid >> 2;
    const int h = tid & 3;

    if (tid == 0) { s_cnt = 0; s_sum = 0.f; }

    // ---- prologue: prefetch tile 0 into registers ----
    float4 rv[6];
    float  gt0p;
    int rowBn = tile0 * TR;
    int nrn   = min(TR, NN - rowBn);
    size_t a0n; int shn, t4n;
    {
        size_t seg = ((size_t)b * NN + rowBn) * CC;
        a0n = seg & ~(size_t)3; shn = (int)(seg - a0n);
        t4n = (shn + nrn * CC + 3) >> 2;
    }
    #pragma unroll
    for (int j = 0; j < 6; ++j) {
        int i = tid + 256 * j;
        if (i < t4n) rv[j] = ld4g(pred_conf, a0n + 4 * (size_t)i, TOTF);
    }
    gt0p = (r < nrn) ? gt_conf[((size_t)b * NN + rowBn + r) * CC] : 1.f;

    for (int t = 0; t < TPB; ++t) {
        const int   c_rowB = rowBn, c_nr = nrn, c_sh = shn, c_t4 = t4n;
        const float c_gt0  = gt0p;
        if (c_rowB >= NN) break;                       // uniform

        __syncthreads();                               // LDS free (prev compute done)
        #pragma unroll
        for (int j = 0; j < 6; ++j) {
            int i = tid + 256 * j;
            if (i < c_t4) l4[i] = rv[j];
        }

        // ---- prefetch next tile (loads overlap compute of current tile) ----
        const int nrowB = (tile0 + t + 1) * TR;
        if (t + 1 < TPB && nrowB < NN) {
            rowBn = nrowB; nrn = min(TR, NN - nrowB);
            size_t seg = ((size_t)b * NN + nrowB) * CC;
            a0n = seg & ~(size_t)3; shn = (int)(seg - a0n);
            t4n = (shn + nrn * CC + 3) >> 2;
            #pragma unroll
            for (int j = 0; j < 6; ++j) {
                int i = tid + 256 * j;
                if (i < t4n) rv[j] = ld4g(pred_conf, a0n + 4 * (size_t)i, TOTF);
            }
            gt0p = (r < nrn) ? gt_conf[((size_t)b * NN + rowBn + r) * CC] : 1.f;
        } else {
            rowBn = NN;                                // sentinel -> break next iter
        }
        __syncthreads();                               // LDS ready

        // ---- compute current tile: quad (4 threads) per row ----
        if (r < c_nr) {
            const int c0 = h * 20 + (h > 0 ? 1 : 0);
            const int nc = (h == 0) ? 21 : 20;
            const float* row = lbuf + c_sh + r * CC;
            const size_t gbase = ((size_t)b * NN + c_rowB + r) * CC;

            float v[21];
            #pragma unroll
            for (int j = 0; j < 21; ++j)
                v[j] = (j < nc) ? row[c0 + j] : -1e30f;

            float m = v[0];
            #pragma unroll
            for (int j = 1; j < 21; ++j) m = fmaxf(m, v[j]);
            m = fmaxf(m, __shfl_xor(m, 1, 64));
            m = fmaxf(m, __shfl_xor(m, 2, 64));

            float e = 0.f;
            #pragma unroll
            for (int j = 0; j < 21; ++j) e += __expf(v[j] - m);   // pad -> exp -> 0
            e += __shfl_xor(e, 1, 64);
            e += __shfl_xor(e, 2, 64);

            const bool pos = (c_gt0 == 0.f);   // background prob 0 => positive prior
            float x_sel = v[0];                // row[0] valid on h==0 (writer lane)
            if (pos) {
                float d = 0.f;
                #pragma unroll
                for (int j = 0; j < 21; ++j)
                    if (j < nc) d += gt_conf[gbase + c0 + j] * v[j];
                d += __shfl_xor(d, 1, 64);
                d += __shfl_xor(d, 2, 64);
                x_sel = d;                     // pred at one-hot label
            }

            const float loss = m + __logf(e) - x_sel;
            if (h == 0) {
                neg_loss[(size_t)b * NN + c_rowB + r] = pos ? 0.f : loss;
                if (pos) { atomicAdd(&s_cnt, 1); atomicAdd(&s_sum, loss); }
            }
        }
    }

    __syncthreads();
    if (tid == 0 && s_cnt) {
        atomicAdd(&num_pos[b], s_cnt);
        atomicAdd(&pos_sum[b], s_sum);
    }
}

// ---------------- per-batch radix select + finalize (atomic mean) ----------------
__global__ __launch_bounds__(256) void select_kernel(
        const float* __restrict__ neg_loss,
        const int*   __restrict__ num_pos,
        const float* __restrict__ pos_sum,
        const float* __restrict__ loc_cnt,
        const float* __restrict__ loc_sum,
        float* __restrict__ out) {
    const int b    = blockIdx.x;
    const int tid  = threadIdx.x;
    const int lane = tid & 63;
    __shared__ unsigned vals[NN];        // 34928 B
    __shared__ unsigned hist[256];
    __shared__ unsigned sh_prefix, sh_r;
    __shared__ float    s_part[4];

    #pragma unroll 4
    for (int i = tid; i < NN; i += 256)
        vals[i] = __float_as_uint(neg_loss[(size_t)b * NN + i]);

    const int np = num_pos[b];
    const int k  = min(3 * np, NN - 1);  // clip(int(num_neg), 0, N-1)
    if (tid == 0) { sh_prefix = 0u; sh_r = (unsigned)k; }
    __syncthreads();

    unsigned prefix_mask = 0u;
    for (int p = 3; p >= 0; --p) {
        const unsigned pref = sh_prefix;
        const unsigned r    = sh_r;
        hist[tid] = 0u;
        __syncthreads();

        // ballot-aggregated histogram: one atomic per distinct bin per wave
        for (int i0 = 0; i0 < NN; i0 += 256) {
            const int i = i0 + tid;
            const bool act = (i < NN) && ((vals[i] & prefix_mask) == pref);
            const unsigned v   = act ? vals[i] : 0u;
            const unsigned bin = (v >> (8 * p)) & 255u;
            unsigned long long mm = __ballot(act);
            #pragma unroll
            for (int bit = 0; bit < 8; ++bit) {
                unsigned long long s = __ballot(act && ((bin >> bit) & 1u));
                mm &= ((bin >> bit) & 1u) ? s : ~s;
            }
            if (act && ((mm & ((1ull << lane) - 1ull)) == 0ull))
                atomicAdd(&hist[bin], (unsigned)__popcll(mm));
        }
        __syncthreads();

        // wave-0 suffix scan over 256 bins (4 bins/lane) + bin pick
        if (tid < 64) {
            const unsigned h0 = hist[4 * tid + 0];
            const unsigned h1 = hist[4 * tid + 1];
            const unsigned h2 = hist[4 * tid + 2];
            const unsigned h3 = hist[4 * tid + 3];
            unsigned T = h0 + h1 + h2 + h3;
            #pragma unroll
            for (int off = 1; off < 64; off <<= 1) {
                unsigned t2 = __shfl_down(T, off, 64);
                if (tid + off < 64) T += t2;
            }
            unsigned Tn = __shfl_down(T, 1, 64);
            if (tid == 63) Tn = 0u;
            const unsigned S4 = Tn, S3 = S4 + h3, S2 = S3 + h2, S1 = S2 + h1, S0 = S1 + h0;
            int bin = -1; unsigned Slo = 0u;
            if      (S1 <= r && r < S0) { bin = 4 * tid + 0; Slo = S1; }
            else if (S2 <= r && r < S1) { bin = 4 * tid + 1; Slo = S2; }
            else if (S3 <= r && r < S2) { bin = 4 * tid + 2; Slo = S3; }
            else if (S4 <= r && r < S3) { bin = 4 * tid + 3; Slo = S4; }
            if (bin >= 0) {
                sh_r = r - Slo;
                sh_prefix = pref | ((unsigned)bin << (8 * p));
            }
        }
        __syncthreads();
        prefix_mask |= 0xFFu << (8 * p);
    }

    const float thresh = __uint_as_float(sh_prefix);   // exact (k+1)-th largest
    float s = 0.f;
    #pragma unroll 4
    for (int i = tid; i < NN; i += 256) {
        float v = __uint_as_float(vals[i]);
        if (v > thresh) s += v;                        // strict >, matches reference
    }
    for (int o = 32; o; o >>= 1) s += __shfl_down(s, o, 64);
    if (lane == 0) s_part[tid >> 6] = s;
    __syncthreads();
    if (tid == 0) {
        float neg_sum = s_part[0] + s_part[1] + s_part[2] + s_part[3];
        float npf = (float)np;
        float res = pos_sum[b] / npf + neg_sum / (3.0f * npf) + loc_sum[b] / loc_cnt[b];
        atomicAdd(out, res * (1.0f / BB));
    }
}

extern "C" void kernel_launch(void* const* d_in, const int* in_sizes, int n_in,
                              void* d_out, int out_size, void* d_ws, size_t ws_size,
                              hipStream_t stream) {
    const float* pred_conf = (const float*)d_in[0];
    const float* pred_loc  = (const float*)d_in[1];
    const float* gt_conf   = (const float*)d_in[2];
    const float* gt_loc    = (const float*)d_in[3];

    float* neg      = (float*)d_ws;                 // B*N floats
    int*   num_pos  = (int*)(neg + (size_t)BB * NN);
    float* pos_sum  = (float*)(num_pos + BB);
    float* loc_cnt  = pos_sum + BB;
    float* loc_sum  = loc_cnt + BB;

    init_kernel<<<1, 256, 0, stream>>>((unsigned*)num_pos, (float*)d_out);

    dim3 fgrid(CBX + LBX, BB);                      // 40 x 64
    fused_kernel<<<fgrid, 256, 0, stream>>>(pred_conf, gt_conf, pred_loc, gt_loc,
                                            neg, num_pos, pos_sum, loc_cnt, loc_sum);

    select_kernel<<<BB, 256, 0, stream>>>(neg, num_pos, pos_sum, loc_cnt, loc_sum,
                                          (float*)d_out);
}

// Round 5
// 414.361 us; speedup vs baseline: 1.1715x; 1.0037x over previous
//
#include <hip/hip_runtime.h>
#include <math.h>

#define BB 64
#define NN 8732
#define CC 81
#define TR 64                       // rows per tile
#define TPB 4                       // tiles per block (software pipeline depth)
#define CBX ((NN + TR * TPB - 1) / (TR * TPB))   // 35 conf blocks per batch
#define LBX 5                       // loc blocks per batch (2048 priors each)

// ---------------- init: zero per-b accumulators + output ----------------
__global__ void init_kernel(unsigned* acc, float* out) {
    int i = threadIdx.x;
    if (i < 4 * BB) acc[i] = 0u;   // num_pos[B], pos_sum[B], loc_cnt[B], loc_sum[B]
    if (i == 0) out[0] = 0.f;
}

__device__ __forceinline__ float4 ld4g(const float* __restrict__ p, size_t gf, size_t TOTF) {
    if (gf + 4 <= TOTF) return *(const float4*)(p + gf);
    float4 r; float* rp = (float*)&r;
    #pragma unroll
    for (int c = 0; c < 4; ++c) rp[c] = (gf + c < TOTF) ? p[gf + c] : 0.f;
    return r;
}

// ---------------- fused conf + loc ----------------
__global__ __launch_bounds__(256) void fused_kernel(
        const float* __restrict__ pred_conf,
        const float* __restrict__ gt_conf,
        const float* __restrict__ pred_loc,
        const float* __restrict__ gt_loc,
        float* __restrict__ neg_loss,
        int* __restrict__ num_pos,
        float* __restrict__ pos_sum,
        float* __restrict__ loc_cnt,
        float* __restrict__ loc_sum) {
    const int b   = blockIdx.y;
    const int tid = threadIdx.x;

    if (blockIdx.x >= CBX) {
        // ================= loc part =================
        const int lb = blockIdx.x - CBX;
        const float4* pl = (const float4*)pred_loc;
        const float4* gl = (const float4*)gt_loc;
        float sum = 0.f, cnt = 0.f;
        #pragma unroll
        for (int j = 0; j < 8; ++j) {
            int n = lb * 2048 + j * 256 + tid;
            if (n < NN) {
                size_t idx = (size_t)b * NN + n;
                float4 p = pl[idx];
                float4 g = gl[idx];
                bool any = false;
                float pv[4] = {p.x, p.y, p.z, p.w};
                float gv[4] = {g.x, g.y, g.z, g.w};
                #pragma unroll
                for (int c = 0; c < 4; ++c) {
                    if (gv[c] != 0.f) {
                        any = true;
                        float d = fabsf(pv[c] - gv[c]);
                        sum += (d < 1.f) ? 0.5f * d * d : d - 0.5f;
                    }
                }
                if (any) cnt += 1.f;
            }
        }
        for (int o = 32; o; o >>= 1) {
            sum += __shfl_down(sum, o, 64);
            cnt += __shfl_down(cnt, o, 64);
        }
        __shared__ float ls_sum, ls_cnt;
        if (tid == 0) { ls_sum = 0.f; ls_cnt = 0.f; }
        __syncthreads();
        if ((tid & 63) == 0) { atomicAdd(&ls_sum, sum); atomicAdd(&ls_cnt, cnt); }
        __syncthreads();
        if (tid == 0) { atomicAdd(&loc_sum[b], ls_sum); atomicAdd(&loc_cnt[b], ls_cnt); }
        return;
    }

    // ================= conf part: software pipeline, prefetch AFTER barrier =================
    __shared__ float lbuf[TR * CC + 8];
    __shared__ int   s_cnt;
    __shared__ float s_sum;
    float4* l4 = (float4*)lbuf;

    const size_t TOTF = (size_t)BB * NN * CC;
    const int tile0 = blockIdx.x * TPB;
    const int r = tid >> 2;
    const int h = tid & 3;

    if (tid == 0) { s_cnt = 0; s_sum = 0.f; }

    // ---- prologue: prefetch tile 0 into registers ----
    float4 rv[6];
    float  gt0p;
    int rowBn = tile0 * TR;
    int nrn   = min(TR, NN - rowBn);
    size_t a0n; int shn, t4n;
    {
        size_t seg = ((size_t)b * NN + rowBn) * CC;
        a0n = seg & ~(size_t)3; shn = (int)(seg - a0n);
        t4n = (shn + nrn * CC + 3) >> 2;
    }
    #pragma unroll
    for (int j = 0; j < 6; ++j) {
        int i = tid + 256 * j;
        if (i < t4n) rv[j] = ld4g(pred_conf, a0n + 4 * (size_t)i, TOTF);
    }
    gt0p = (r < nrn) ? gt_conf[((size_t)b * NN + rowBn + r) * CC] : 1.f;

    for (int t = 0; t < TPB; ++t) {
        const int   c_rowB = rowBn, c_nr = nrn, c_sh = shn, c_t4 = t4n;
        const float c_gt0  = gt0p;
        if (c_rowB >= NN) break;                       // uniform

        __syncthreads();                               // LDS free (prev compute done)
        #pragma unroll
        for (int j = 0; j < 6; ++j) {                  // consumes rv (vmcnt wait here)
            int i = tid + 256 * j;
            if (i < c_t4) l4[i] = rv[j];
        }
        __syncthreads();                               // LDS ready; nothing in flight -> cheap drain

        // ---- prefetch next tile AFTER the barrier: overlaps compute below ----
        const int nrowB = (tile0 + t + 1) * TR;
        if (t + 1 < TPB && nrowB < NN) {
            rowBn = nrowB; nrn = min(TR, NN - nrowB);
            size_t seg = ((size_t)b * NN + nrowB) * CC;
            a0n = seg & ~(size_t)3; shn = (int)(seg - a0n);
            t4n = (shn + nrn * CC + 3) >> 2;
            #pragma unroll
            for (int j = 0; j < 6; ++j) {
                int i = tid + 256 * j;
                if (i < t4n) rv[j] = ld4g(pred_conf, a0n + 4 * (size_t)i, TOTF);
            }
            gt0p = (r < nrn) ? gt_conf[((size_t)b * NN + rowBn + r) * CC] : 1.f;
        } else {
            rowBn = NN;                                // sentinel -> break next iter
        }

        // ---- compute current tile: quad (4 threads) per row ----
        if (r < c_nr) {
            const int c0 = h * 20 + (h > 0 ? 1 : 0);
            const int nc = (h == 0) ? 21 : 20;
            const float* row = lbuf + c_sh + r * CC;
            const size_t gbase = ((size_t)b * NN + c_rowB + r) * CC;

            float v[21];
            #pragma unroll
            for (int j = 0; j < 21; ++j)
                v[j] = (j < nc) ? row[c0 + j] : -1e30f;

            float m = v[0];
            #pragma unroll
            for (int j = 1; j < 21; ++j) m = fmaxf(m, v[j]);
            m = fmaxf(m, __shfl_xor(m, 1, 64));
            m = fmaxf(m, __shfl_xor(m, 2, 64));

            float e = 0.f;
            #pragma unroll
            for (int j = 0; j < 21; ++j) e += __expf(v[j] - m);   // pad -> exp -> 0
            e += __shfl_xor(e, 1, 64);
            e += __shfl_xor(e, 2, 64);

            const bool pos = (c_gt0 == 0.f);   // background prob 0 => positive prior
            float x_sel = v[0];                // row[0] valid on h==0 (writer lane)
            if (pos) {
                float d = 0.f;
                #pragma unroll
                for (int j = 0; j < 21; ++j)
                    if (j < nc) d += gt_conf[gbase + c0 + j] * v[j];
                d += __shfl_xor(d, 1, 64);
                d += __shfl_xor(d, 2, 64);
                x_sel = d;                     // pred at one-hot label
            }

            const float loss = m + __logf(e) - x_sel;
            if (h == 0) {
                neg_loss[(size_t)b * NN + c_rowB + r] = pos ? 0.f : loss;
                if (pos) { atomicAdd(&s_cnt, 1); atomicAdd(&s_sum, loss); }
            }
        }
    }

    __syncthreads();
    if (tid == 0 && s_cnt) {
        atomicAdd(&num_pos[b], s_cnt);
        atomicAdd(&pos_sum[b], s_sum);
    }
}

// ---------------- per-batch radix select + finalize (atomic mean) ----------------
__global__ __launch_bounds__(256) void select_kernel(
        const float* __restrict__ neg_loss,
        const int*   __restrict__ num_pos,
        const float* __restrict__ pos_sum,
        const float* __restrict__ loc_cnt,
        const float* __restrict__ loc_sum,
        float* __restrict__ out) {
    const int b    = blockIdx.x;
    const int tid  = threadIdx.x;
    const int lane = tid & 63;
    __shared__ unsigned vals[NN];        // 34928 B
    __shared__ unsigned hist[256];
    __shared__ unsigned sh_prefix, sh_r;
    __shared__ float    s_part[4];

    #pragma unroll 4
    for (int i = tid; i < NN; i += 256)
        vals[i] = __float_as_uint(neg_loss[(size_t)b * NN + i]);

    const int np = num_pos[b];
    const int k  = min(3 * np, NN - 1);  // clip(int(num_neg), 0, N-1)
    if (tid == 0) { sh_prefix = 0u; sh_r = (unsigned)k; }
    __syncthreads();

    unsigned prefix_mask = 0u;
    for (int p = 3; p >= 0; --p) {
        const unsigned pref = sh_prefix;
        const unsigned r    = sh_r;
        hist[tid] = 0u;
        __syncthreads();

        // ballot-aggregated histogram: one atomic per distinct bin per wave
        for (int i0 = 0; i0 < NN; i0 += 256) {
            const int i = i0 + tid;
            const bool act = (i < NN) && ((vals[i] & prefix_mask) == pref);
            const unsigned v   = act ? vals[i] : 0u;
            const unsigned bin = (v >> (8 * p)) & 255u;
            unsigned long long mm = __ballot(act);
            #pragma unroll
            for (int bit = 0; bit < 8; ++bit) {
                unsigned long long s = __ballot(act && ((bin >> bit) & 1u));
                mm &= ((bin >> bit) & 1u) ? s : ~s;
            }
            if (act && ((mm & ((1ull << lane) - 1ull)) == 0ull))
                atomicAdd(&hist[bin], (unsigned)__popcll(mm));
        }
        __syncthreads();

        // wave-0 suffix scan over 256 bins (4 bins/lane) + bin pick
        if (tid < 64) {
            const unsigned h0 = hist[4 * tid + 0];
            const unsigned h1 = hist[4 * tid + 1];
            const unsigned h2 = hist[4 * tid + 2];
            const unsigned h3 = hist[4 * tid + 3];
            unsigned T = h0 + h1 + h2 + h3;
            #pragma unroll
            for (int off = 1; off < 64; off <<= 1) {
                unsigned t2 = __shfl_down(T, off, 64);
                if (tid + off < 64) T += t2;
            }
            unsigned Tn = __shfl_down(T, 1, 64);
            if (tid == 63) Tn = 0u;
            const unsigned S4 = Tn, S3 = S4 + h3, S2 = S3 + h2, S1 = S2 + h1, S0 = S1 + h0;
            int bin = -1; unsigned Slo = 0u;
            if      (S1 <= r && r < S0) { bin = 4 * tid + 0; Slo = S1; }
            else if (S2 <= r && r < S1) { bin = 4 * tid + 1; Slo = S2; }
            else if (S3 <= r && r < S2) { bin = 4 * tid + 2; Slo = S3; }
            else if (S4 <= r && r < S3) { bin = 4 * tid + 3; Slo = S4; }
            if (bin >= 0) {
                sh_r = r - Slo;
                sh_prefix = pref | ((unsigned)bin << (8 * p));
            }
        }
        __syncthreads();
        prefix_mask |= 0xFFu << (8 * p);
    }

    const float thresh = __uint_as_float(sh_prefix);   // exact (k+1)-th largest
    float s = 0.f;
    #pragma unroll 4
    for (int i = tid; i < NN; i += 256) {
        float v = __uint_as_float(vals[i]);
        if (v > thresh) s += v;                        // strict >, matches reference
    }
    for (int o = 32; o; o >>= 1) s += __shfl_down(s, o, 64);
    if (lane == 0) s_part[tid >> 6] = s;
    __syncthreads();
    if (tid == 0) {
        float neg_sum = s_part[0] + s_part[1] + s_part[2] + s_part[3];
        float npf = (float)np;
        float res = pos_sum[b] / npf + neg_sum / (3.0f * npf) + loc_sum[b] / loc_cnt[b];
        atomicAdd(out, res * (1.0f / BB));
    }
}

extern "C" void kernel_launch(void* const* d_in, const int* in_sizes, int n_in,
                              void* d_out, int out_size, void* d_ws, size_t ws_size,
                              hipStream_t stream) {
    const float* pred_conf = (const float*)d_in[0];
    const float* pred_loc  = (const float*)d_in[1];
    const float* gt_conf   = (const float*)d_in[2];
    const float* gt_loc    = (const float*)d_in[3];

    float* neg      = (float*)d_ws;                 // B*N floats
    int*   num_pos  = (int*)(neg + (size_t)BB * NN);
    float* pos_sum  = (float*)(num_pos + BB);
    float* loc_cnt  = pos_sum + BB;
    float* loc_sum  = loc_cnt + BB;

    init_kernel<<<1, 256, 0, stream>>>((unsigned*)num_pos, (float*)d_out);

    dim3 fgrid(CBX + LBX, BB);                      // 40 x 64
    fused_kernel<<<fgrid, 256, 0, stream>>>(pred_conf, gt_conf, pred_loc, gt_loc,
                                            neg, num_pos, pos_sum, loc_cnt, loc_sum);

    select_kernel<<<BB, 256, 0, stream>>>(neg, num_pos, pos_sum, loc_cnt, loc_sum,
                                          (float*)d_out);
}